// Round 12
// baseline (155.962 us; speedup 1.0000x reference)
//
#include <hip/hip_runtime.h>

#define BB 8
#define CC 256
#define HH 64
#define WW 64
#define RED 64
#define HW 4096   // HH*WW
#define AST 72    // xs bf16 row stride ([px][c] layout, 16B-aligned rows)
#define LS 68     // LDS row stride for image planes in invol_dw
#define G  4      // channels per invol_dw block (kern-register amortization)

typedef __attribute__((ext_vector_type(8))) short s8v;   // 8 bf16 (4 VGPRs)
typedef __attribute__((ext_vector_type(4))) float f4v;   // MFMA accumulator

__device__ __forceinline__ unsigned short f2bf(float f) {  // RNE f32->bf16
    unsigned u = __float_as_uint(f);
    u += 0x7fff + ((u >> 16) & 1);
    return (unsigned short)(u >> 16);
}

// ---- fused dwconv1 + involution-kernel-generation, MFMA phase B ----
// One block per (row h, batch b): 512 threads = 8 waves.
// Phase A: dwconv1 for a 64-channel chunk -> bf16 LDS tile xs[px][c].
// Phase B: [64px x 64c]x[64c x 64o] via mfma_f32_16x16x32_bf16; wave w =
// (mt = w&3, nh = w>>2). B-frags gathered straight from w_red (L2-resident,
// 32B contiguous per lane) with in-reg bf16 convert -- no build_wtf launch,
// no in-loop SMEM/LDS weight feed.
__global__ __launch_bounds__(512, 4) void dw_kern(const float* __restrict__ x,
                                                  const float* __restrict__ w_in,
                                                  const float* __restrict__ b_in,
                                                  const float* __restrict__ w_red,   // [64][256]
                                                  const float* __restrict__ b_red,
                                                  const float* __restrict__ w_span,  // [9][64]
                                                  const float* __restrict__ b_span,
                                                  float* __restrict__ kern) {
    alignas(16) __shared__ char smem[16640 + 18432];     // 35 KB
    unsigned short* xs = (unsigned short*)smem;          // [64px][AST] bf16 (9.2 KB)
    float* r_lds = (float*)smem;                         // [64o][65] f32, aliases xs (dead)
    float* part  = (float*)(smem + 16640);               // [8og][9][64px]

    const int t  = threadIdx.x;
    const int bx = blockIdx.x;
    const int h  = ((bx & 7) << 3) | (bx >> 3);  // XCD band swizzle
    const int b  = blockIdx.y;
    const int l  = t & 63;                       // lane
    const int wv = t >> 6;                       // wave 0..7
    const int mt = wv & 3, nh = wv >> 2;
    const int m0 = mt << 4;
    // phase-A mapping: 16 col-quads x 32 channel-rows
    const int q  = t & 15;
    const int w0 = q << 2;
    const int cr = t >> 4;                       // 0..31

    float4 pv[2][3]; float plf[2][3], prt[2][3]; // x-row prefetch regs

    auto loadX = [&](int c0) {
        #pragma unroll
        for (int s = 0; s < 2; s++) {
            const int cc = c0 + s * 32 + cr;
            const float* xp = x + ((size_t)(b * CC + cc)) * HW;
            #pragma unroll
            for (int ky = 0; ky < 3; ky++) {
                int hh = h + ky - 1;
                if (hh < 0 || hh >= HH) {        // block-uniform branch
                    pv[s][ky] = make_float4(0.f, 0.f, 0.f, 0.f);
                    plf[s][ky] = 0.f; prt[s][ky] = 0.f;
                    continue;
                }
                const float* row = xp + hh * WW + w0;
                pv[s][ky]  = *(const float4*)row;
                plf[s][ky] = (w0 > 0)      ? row[-1] : 0.f;
                prt[s][ky] = (w0 + 4 < WW) ? row[4]  : 0.f;
            }
        }
    };
    auto computeA = [&](int c0) {                // dwconv from regs -> bf16 xs
        #pragma unroll
        for (int s = 0; s < 2; s++) {
            const int cl = s * 32 + cr;
            const int cc = c0 + cl;
            const float* wp = w_in + cc * 9;
            const float bb = b_in[cc];
            float4 a4 = make_float4(bb, bb, bb, bb);
            #pragma unroll
            for (int ky = 0; ky < 3; ky++) {
                float4 v = pv[s][ky];
                float lf = plf[s][ky], rt = prt[s][ky];
                float k0 = wp[ky * 3 + 0], k1 = wp[ky * 3 + 1], k2 = wp[ky * 3 + 2];
                a4.x = fmaf(k0, lf,  a4.x); a4.y = fmaf(k0, v.x, a4.y);
                a4.z = fmaf(k0, v.y, a4.z); a4.w = fmaf(k0, v.z, a4.w);
                a4.x = fmaf(k1, v.x, a4.x); a4.y = fmaf(k1, v.y, a4.y);
                a4.z = fmaf(k1, v.z, a4.z); a4.w = fmaf(k1, v.w, a4.w);
                a4.x = fmaf(k2, v.y, a4.x); a4.y = fmaf(k2, v.z, a4.y);
                a4.z = fmaf(k2, v.w, a4.z); a4.w = fmaf(k2, rt,  a4.w);
            }
            xs[(w0 + 0) * AST + cl] = f2bf(a4.x);   // [px][c] for A-frag reads
            xs[(w0 + 1) * AST + cl] = f2bf(a4.y);
            xs[(w0 + 2) * AST + cl] = f2bf(a4.z);
            xs[(w0 + 3) * AST + cl] = f2bf(a4.w);
        }
    };

    s8v bfr[2][2];                               // B-frags [kb][ntl] for current chunk
    auto loadB = [&](int k) {                    // gather from w_red + in-reg cvt
        #pragma unroll
        for (int kb = 0; kb < 2; kb++)
            #pragma unroll
            for (int ntl = 0; ntl < 2; ntl++) {
                int o = ((nh << 1) + ntl) * 16 + (l & 15);
                int c = (k << 6) + (kb << 5) + ((l >> 4) & 3) * 8;
                const float* wp = w_red + o * CC + c;    // 32B contiguous per lane
                float4 a  = *(const float4*)wp;
                float4 b4 = *(const float4*)(wp + 4);
                s8v f;
                f[0] = (short)f2bf(a.x);  f[1] = (short)f2bf(a.y);
                f[2] = (short)f2bf(a.z);  f[3] = (short)f2bf(a.w);
                f[4] = (short)f2bf(b4.x); f[5] = (short)f2bf(b4.y);
                f[6] = (short)f2bf(b4.z); f[7] = (short)f2bf(b4.w);
                bfr[kb][ntl] = f;
            }
    };

    f4v acc[2] = {{0.f, 0.f, 0.f, 0.f}, {0.f, 0.f, 0.f, 0.f}};

    loadX(0); loadB(0);
    for (int k = 0; k < 4; k++) {
        computeA(k << 6);                        // regs -> xs (bf16)
        if (k < 3) loadX((k + 1) << 6);          // VMEM issue for next chunk
        __syncthreads();
        // phase B: 2 A-frag ds_read_b128 + 4 MFMA per wave
        #pragma unroll
        for (int kb = 0; kb < 2; kb++) {
            const unsigned short* ap =
                xs + (m0 + (l & 15)) * AST + (kb << 5) + ((l >> 4) & 3) * 8;
            s8v av = *(const s8v*)ap;
            #pragma unroll
            for (int ntl = 0; ntl < 2; ntl++)
                acc[ntl] = __builtin_amdgcn_mfma_f32_16x16x32_bf16(
                    av, bfr[kb][ntl], acc[ntl], 0, 0, 0);
        }
        if (k < 3) loadB(k + 1);
        __syncthreads();                         // xs consumed; safe to overwrite
    }

    // C-frags -> r_lds[o][65] (aliases dead xs)
    #pragma unroll
    for (int ntl = 0; ntl < 2; ntl++) {
        int o = ((nh << 1) + ntl) * 16 + (l & 15);
        int pxr = m0 + ((l >> 4) & 3) * 4;       // row = (lane>>4)*4 + i
        #pragma unroll
        for (int i = 0; i < 4; i++)
            r_lds[o * 65 + pxr + i] = acc[ntl][i];
    }
    __syncthreads();

    // epilogue: relu + span contraction + cross-o-group reduction (og = wave)
    const int px = t & 63;
    const int o0 = __builtin_amdgcn_readfirstlane(wv << 3);
    float kk[9];
    #pragma unroll
    for (int j = 0; j < 9; j++) kk[j] = 0.f;
    #pragma unroll
    for (int i = 0; i < 8; i++) {
        float r = fmaxf(r_lds[(o0 + i) * 65 + px] + b_red[o0 + i], 0.f);
        #pragma unroll
        for (int j = 0; j < 9; j++) kk[j] = fmaf(w_span[j * RED + o0 + i], r, kk[j]);
    }
    #pragma unroll
    for (int j = 0; j < 9; j++) part[(wv * 9 + j) * 64 + px] = kk[j];
    __syncthreads();
    if (wv == 0) {
        float* kp = kern + (size_t)b * 9 * HW + h * WW + px;
        #pragma unroll
        for (int j = 0; j < 9; j++) {
            float s = b_span[j];
            #pragma unroll
            for (int g = 0; g < 8; g++) s += part[(g * 9 + j) * 64 + px];
            kp[j * HW] = s;
        }
    }
}

// ---- fused dwconv1(recompute) + involution-apply + dwconv2, G channels ----
// One block per (channel-group, b): 1024 threads x 4 px (full 64x64 plane).
// kern for this thread's 4 px loaded ONCE into registers (36 VGPRs) and
// reused across G channels -> kern L2 traffic / G, kern VMEM instrs / G.
// Per channel: stage x -> dwconv1 -> involution (kern regs) -> dwconv2.
__global__ __launch_bounds__(1024, 4) void invol_dw(const float* __restrict__ x,
                                                    const float* __restrict__ w_in,
                                                    const float* __restrict__ b_in,
                                                    const float* __restrict__ kern,
                                                    const float* __restrict__ w_out,
                                                    const float* __restrict__ b_out,
                                                    float* __restrict__ out) {
    __shared__ float xs[HH * LS];                // x stage, later involution result
    __shared__ float x1s[HH * LS];               // dwconv1 output
    const int t  = threadIdx.x;
    const int r  = t >> 4;                       // row 0..63
    const int w0 = (t & 15) << 2;                // col quad
    const int cg = blockIdx.x;                   // channel group 0..63
    const int b  = blockIdx.y;
    const int hw = r * WW + w0;

    // kern fragment for this thread's 4 px (reused across G channels)
    float4 kv[9];
    {
        const float* kp = kern + (size_t)b * 9 * HW + hw;
        #pragma unroll
        for (int j = 0; j < 9; j++) kv[j] = *(const float4*)(kp + j * HW);
    }

    for (int g = 0; g < G; g++) {
        const int c = cg * G + g;
        const float* xp = x + ((size_t)(b * CC + c)) * HW;

        // stage x plane (1 float4/thread, coalesced)
        *(float4*)&xs[r * LS + w0] = *(const float4*)(xp + hw);
        __syncthreads();

        // dwconv1: x1s = dwconv(xs, w_in[c]) + b_in[c]
        {
            const float* wp = w_in + c * 9;      // block-uniform -> s_load
            const float bb = b_in[c];
            float4 acc = make_float4(bb, bb, bb, bb);
            #pragma unroll
            for (int ky = 0; ky < 3; ky++) {
                int hh = r + ky - 1;
                if (hh < 0 || hh >= HH) continue;
                const float* row = &xs[hh * LS + w0];
                float4 v = *(const float4*)row;
                float lf = (w0 > 0)      ? row[-1] : 0.f;
                float rt = (w0 + 4 < WW) ? row[4]  : 0.f;
                float k0 = wp[ky * 3 + 0], k1 = wp[ky * 3 + 1], k2 = wp[ky * 3 + 2];
                acc.x = fmaf(k0, lf,  acc.x); acc.y = fmaf(k0, v.x, acc.y);
                acc.z = fmaf(k0, v.y, acc.z); acc.w = fmaf(k0, v.z, acc.w);
                acc.x = fmaf(k1, v.x, acc.x); acc.y = fmaf(k1, v.y, acc.y);
                acc.z = fmaf(k1, v.z, acc.z); acc.w = fmaf(k1, v.w, acc.w);
                acc.x = fmaf(k2, v.y, acc.x); acc.y = fmaf(k2, v.z, acc.y);
                acc.z = fmaf(k2, v.w, acc.z); acc.w = fmaf(k2, rt,  acc.w);
            }
            *(float4*)&x1s[r * LS + w0] = acc;
        }
        __syncthreads();

        // involution from x1s (kern in regs) -> xs (x stage dead)
        {
            float4 acc = make_float4(0.f, 0.f, 0.f, 0.f);
            #pragma unroll
            for (int ky = 0; ky < 3; ky++) {
                int hh = r + ky - 1;
                if (hh < 0 || hh >= HH) continue;
                const float* row = &x1s[hh * LS + w0];
                float4 v = *(const float4*)row;
                float lf = (w0 > 0)      ? row[-1] : 0.f;
                float rt = (w0 + 4 < WW) ? row[4]  : 0.f;
                float4 k0 = kv[ky * 3 + 0], k1 = kv[ky * 3 + 1], k2 = kv[ky * 3 + 2];
                acc.x = fmaf(k0.x, lf,  acc.x); acc.y = fmaf(k0.y, v.x, acc.y);
                acc.z = fmaf(k0.z, v.y, acc.z); acc.w = fmaf(k0.w, v.z, acc.w);
                acc.x = fmaf(k1.x, v.x, acc.x); acc.y = fmaf(k1.y, v.y, acc.y);
                acc.z = fmaf(k1.z, v.z, acc.z); acc.w = fmaf(k1.w, v.w, acc.w);
                acc.x = fmaf(k2.x, v.y, acc.x); acc.y = fmaf(k2.y, v.z, acc.y);
                acc.z = fmaf(k2.z, v.w, acc.z); acc.w = fmaf(k2.w, rt,  acc.w);
            }
            __syncthreads();                     // x1s consumers done before xs overwrite?
            *(float4*)&xs[r * LS + w0] = acc;    // (xs dead: dwconv1 readers finished)
        }
        __syncthreads();

        // dwconv2 from xs (involution result) -> global out
        {
            const float* wp = w_out + c * 9;     // block-uniform -> s_load
            const float bb = b_out[c];
            float4 acc = make_float4(bb, bb, bb, bb);
            #pragma unroll
            for (int ky = 0; ky < 3; ky++) {
                int hh = r + ky - 1;
                if (hh < 0 || hh >= HH) continue;
                const float* row = &xs[hh * LS + w0];
                float4 v = *(const float4*)row;
                float lf = (w0 > 0)      ? row[-1] : 0.f;
                float rt = (w0 + 4 < WW) ? row[4]  : 0.f;
                float k0 = wp[ky * 3 + 0], k1 = wp[ky * 3 + 1], k2 = wp[ky * 3 + 2];
                acc.x = fmaf(k0, lf,  acc.x); acc.y = fmaf(k0, v.x, acc.y);
                acc.z = fmaf(k0, v.y, acc.z); acc.w = fmaf(k0, v.z, acc.w);
                acc.x = fmaf(k1, v.x, acc.x); acc.y = fmaf(k1, v.y, acc.y);
                acc.z = fmaf(k1, v.z, acc.z); acc.w = fmaf(k1, v.w, acc.w);
                acc.x = fmaf(k2, v.y, acc.x); acc.y = fmaf(k2, v.z, acc.y);
                acc.z = fmaf(k2, v.w, acc.z); acc.w = fmaf(k2, rt,  acc.w);
            }
            *(float4*)(out + ((size_t)(b * CC + c)) * HW + hw) = acc;
        }
        __syncthreads();                         // all dwconv2 reads done before next stage
    }
}

extern "C" void kernel_launch(void* const* d_in, const int* in_sizes, int n_in,
                              void* d_out, int out_size, void* d_ws, size_t ws_size,
                              hipStream_t stream) {
    const float* x      = (const float*)d_in[0];
    const float* w_in   = (const float*)d_in[1];
    const float* b_in   = (const float*)d_in[2];
    const float* w_red  = (const float*)d_in[3];
    const float* b_red  = (const float*)d_in[4];
    const float* w_span = (const float*)d_in[5];
    const float* b_span = (const float*)d_in[6];
    const float* w_out  = (const float*)d_in[7];
    const float* b_out  = (const float*)d_in[8];
    float* out = (float*)d_out;

    float* kern = (float*)d_ws;                        // 8*9*4096 f

    dw_kern<<<dim3(HH, BB), 512, 0, stream>>>(x, w_in, b_in, w_red, b_red,
                                              w_span, b_span, kern);
    invol_dw<<<dim3(CC / G, BB), 1024, 0, stream>>>(x, w_in, b_in, kern,
                                                    w_out, b_out, out);
}

// Round 14
// 136.354 us; speedup vs baseline: 1.1438x; 1.1438x over previous
//
#include <hip/hip_runtime.h>

#define BB 8
#define CC 256
#define HH 64
#define WW 64
#define RED 64
#define HW 4096   // HH*WW
#define AST 72    // xs bf16 row stride ([px][c] layout, 16B-aligned rows)
#define LS 68     // LDS row stride for image planes in invol_dw

typedef __attribute__((ext_vector_type(8))) short s8v;   // 8 bf16 (4 VGPRs)
typedef __attribute__((ext_vector_type(4))) float f4v;   // MFMA accumulator

__device__ __forceinline__ unsigned short f2bf(float f) {  // RNE f32->bf16
    unsigned u = __float_as_uint(f);
    u += 0x7fff + ((u >> 16) & 1);
    return (unsigned short)(u >> 16);
}

// ---- build w_red in B-fragment order (bf16) ----
// wtf[e], e = ((kbg*4 + nt)*64 + lane)*8 + j  holds  B[k][n] = w_red[o=n][c=k]
// with n = nt*16 + (lane&15), k = kbg*32 + (lane>>4)*8 + j.  32 KB, L2-resident.
__global__ __launch_bounds__(256) void build_wtf(const float* __restrict__ w_red,
                                                 unsigned short* __restrict__ wtf) {
    int e = blockIdx.x * 256 + threadIdx.x;      // 64 blocks -> 16384
    int j = e & 7, l = (e >> 3) & 63, nt = (e >> 9) & 3, kbg = e >> 11;
    int o = nt * 16 + (l & 15);
    int c = kbg * 32 + ((l >> 4) & 3) * 8 + j;
    wtf[e] = f2bf(w_red[o * CC + c]);
}

// ---- fused dwconv1 + involution-kernel-generation, MFMA phase B ----
// One block per (row h, batch b): 512 threads = 8 waves.
// Phase A: dwconv1 for a 64-channel chunk -> bf16 LDS tile xs[px][c].
// Phase B: [64px x 64c]x[64c x 64o] via mfma_f32_16x16x32_bf16; wave w =
// (mt = w&3, nh = w>>2) computes px-strip mt*16.. x o-halves nh*32..
// B-frags come straight from global (L2) in fragment order -> no in-loop
// SMEM/LDS weight feed.  [R12/R13 variants of this loop both regressed or
// broke -- this two-barrier shape is the verified one; do not re-pipeline.]
__global__ __launch_bounds__(512, 4) void dw_kern(const float* __restrict__ x,
                                                  const float* __restrict__ w_in,
                                                  const float* __restrict__ b_in,
                                                  const unsigned short* __restrict__ wtf,
                                                  const float* __restrict__ b_red,
                                                  const float* __restrict__ w_span,  // [9][64]
                                                  const float* __restrict__ b_span,
                                                  float* __restrict__ kern) {
    alignas(16) __shared__ char smem[16640 + 18432];     // 35 KB
    unsigned short* xs = (unsigned short*)smem;          // [64px][AST] bf16 (9.2 KB)
    float* r_lds = (float*)smem;                         // [64o][65] f32, aliases xs (dead)
    float* part  = (float*)(smem + 16640);               // [8og][9][64px]

    const int t  = threadIdx.x;
    const int bx = blockIdx.x;
    const int h  = ((bx & 7) << 3) | (bx >> 3);  // XCD band swizzle
    const int b  = blockIdx.y;
    const int l  = t & 63;                       // lane
    const int wv = t >> 6;                       // wave 0..7
    const int mt = wv & 3, nh = wv >> 2;
    const int m0 = mt << 4;
    // phase-A mapping: 16 col-quads x 32 channel-rows
    const int q  = t & 15;
    const int w0 = q << 2;
    const int cr = t >> 4;                       // 0..31

    float4 pv[2][3]; float plf[2][3], prt[2][3]; // x-row prefetch regs

    auto loadX = [&](int c0) {
        #pragma unroll
        for (int s = 0; s < 2; s++) {
            const int cc = c0 + s * 32 + cr;
            const float* xp = x + ((size_t)(b * CC + cc)) * HW;
            #pragma unroll
            for (int ky = 0; ky < 3; ky++) {
                int hh = h + ky - 1;
                if (hh < 0 || hh >= HH) {        // block-uniform branch
                    pv[s][ky] = make_float4(0.f, 0.f, 0.f, 0.f);
                    plf[s][ky] = 0.f; prt[s][ky] = 0.f;
                    continue;
                }
                const float* row = xp + hh * WW + w0;
                pv[s][ky]  = *(const float4*)row;
                plf[s][ky] = (w0 > 0)      ? row[-1] : 0.f;
                prt[s][ky] = (w0 + 4 < WW) ? row[4]  : 0.f;
            }
        }
    };
    auto computeA = [&](int c0) {                // dwconv from regs -> bf16 xs
        #pragma unroll
        for (int s = 0; s < 2; s++) {
            const int cl = s * 32 + cr;
            const int cc = c0 + cl;
            const float* wp = w_in + cc * 9;
            const float bb = b_in[cc];
            float4 a4 = make_float4(bb, bb, bb, bb);
            #pragma unroll
            for (int ky = 0; ky < 3; ky++) {
                float4 v = pv[s][ky];
                float lf = plf[s][ky], rt = prt[s][ky];
                float k0 = wp[ky * 3 + 0], k1 = wp[ky * 3 + 1], k2 = wp[ky * 3 + 2];
                a4.x = fmaf(k0, lf,  a4.x); a4.y = fmaf(k0, v.x, a4.y);
                a4.z = fmaf(k0, v.y, a4.z); a4.w = fmaf(k0, v.z, a4.w);
                a4.x = fmaf(k1, v.x, a4.x); a4.y = fmaf(k1, v.y, a4.y);
                a4.z = fmaf(k1, v.z, a4.z); a4.w = fmaf(k1, v.w, a4.w);
                a4.x = fmaf(k2, v.y, a4.x); a4.y = fmaf(k2, v.z, a4.y);
                a4.z = fmaf(k2, v.w, a4.z); a4.w = fmaf(k2, rt,  a4.w);
            }
            xs[(w0 + 0) * AST + cl] = f2bf(a4.x);   // [px][c] for A-frag reads
            xs[(w0 + 1) * AST + cl] = f2bf(a4.y);
            xs[(w0 + 2) * AST + cl] = f2bf(a4.z);
            xs[(w0 + 3) * AST + cl] = f2bf(a4.w);
        }
    };

    s8v bfr[2][2];                               // B-frags [kb][ntl] for current chunk
    auto loadB = [&](int k) {
        #pragma unroll
        for (int kb = 0; kb < 2; kb++)
            #pragma unroll
            for (int ntl = 0; ntl < 2; ntl++) {
                int nt = (nh << 1) + ntl;
                int kbg = (k << 1) + kb;
                bfr[kb][ntl] = *(const s8v*)(wtf + (((kbg * 4 + nt) * 64 + l) << 3));
            }
    };

    f4v acc[2] = {{0.f, 0.f, 0.f, 0.f}, {0.f, 0.f, 0.f, 0.f}};

    loadX(0); loadB(0);
    for (int k = 0; k < 4; k++) {
        computeA(k << 6);                        // regs -> xs (bf16)
        if (k < 3) loadX((k + 1) << 6);          // VMEM issue for next chunk
        __syncthreads();
        // phase B: 2 A-frag ds_read_b128 + 4 MFMA per wave
        #pragma unroll
        for (int kb = 0; kb < 2; kb++) {
            const unsigned short* ap =
                xs + (m0 + (l & 15)) * AST + (kb << 5) + ((l >> 4) & 3) * 8;
            s8v av = *(const s8v*)ap;
            #pragma unroll
            for (int ntl = 0; ntl < 2; ntl++)
                acc[ntl] = __builtin_amdgcn_mfma_f32_16x16x32_bf16(
                    av, bfr[kb][ntl], acc[ntl], 0, 0, 0);
        }
        if (k < 3) loadB(k + 1);
        __syncthreads();                         // xs consumed; safe to overwrite
    }

    // C-frags -> r_lds[o][65] (aliases dead xs)
    #pragma unroll
    for (int ntl = 0; ntl < 2; ntl++) {
        int o = ((nh << 1) + ntl) * 16 + (l & 15);
        int pxr = m0 + ((l >> 4) & 3) * 4;       // row = (lane>>4)*4 + i
        #pragma unroll
        for (int i = 0; i < 4; i++)
            r_lds[o * 65 + pxr + i] = acc[ntl][i];
    }
    __syncthreads();

    // epilogue: relu + span contraction + cross-o-group reduction (og = wave)
    const int px = t & 63;
    const int o0 = __builtin_amdgcn_readfirstlane(wv << 3);
    float kk[9];
    #pragma unroll
    for (int j = 0; j < 9; j++) kk[j] = 0.f;
    #pragma unroll
    for (int i = 0; i < 8; i++) {
        float r = fmaxf(r_lds[(o0 + i) * 65 + px] + b_red[o0 + i], 0.f);
        #pragma unroll
        for (int j = 0; j < 9; j++) kk[j] = fmaf(w_span[j * RED + o0 + i], r, kk[j]);
    }
    #pragma unroll
    for (int j = 0; j < 9; j++) part[(wv * 9 + j) * 64 + px] = kk[j];
    __syncthreads();
    if (wv == 0) {
        float* kp = kern + (size_t)b * 9 * HW + h * WW + px;
        #pragma unroll
        for (int j = 0; j < 9; j++) {
            float s = b_span[j];
            #pragma unroll
            for (int g = 0; g < 8; g++) s += part[(g * 9 + j) * 64 + px];
            kp[j * HW] = s;
        }
    }
}

// ---- fused dwconv1(recompute) + involution-apply + dwconv2 ----
// One block per (c,b) plane: 256 threads x 16 px (4 waves; R12's 1024-thread
// variant regressed on barrier-wave cost). Stages the ORIGINAL x plane,
// recomputes dwconv1 in-LDS (x1 never touches HBM), applies the involution
// (into the dead xs buffer), then dwconv2 from LDS, writes final output.
__global__ __launch_bounds__(256) void invol_dw(const float* __restrict__ x,
                                                const float* __restrict__ w_in,
                                                const float* __restrict__ b_in,
                                                const float* __restrict__ kern,
                                                const float* __restrict__ w_out,
                                                const float* __restrict__ b_out,
                                                float* __restrict__ out) {
    __shared__ float xs[HH * LS];                // x, later involution result
    __shared__ float x1s[HH * LS];               // dwconv1 output
    const int t  = threadIdx.x;
    const int q  = t & 15;
    const int w0 = q << 2;
    const int r  = t >> 4;                       // 0..15
    const int c = blockIdx.x, b = blockIdx.y;
    const float* xp = x + ((size_t)(b * CC + c)) * HW;

    #pragma unroll
    for (int i = 0; i < 4; i++) {
        int h = r + (i << 4);
        *(float4*)&xs[h * LS + w0] = *(const float4*)(xp + h * WW + w0);
    }
    __syncthreads();

    {
        const float* wp = w_in + c * 9;          // block-uniform -> s_load
        const float bb = b_in[c];
        #pragma unroll
        for (int i = 0; i < 4; i++) {
            int h = r + (i << 4);
            float4 acc = make_float4(bb, bb, bb, bb);
            #pragma unroll
            for (int ky = 0; ky < 3; ky++) {
                int hh = h + ky - 1;
                if (hh < 0 || hh >= HH) continue;
                const float* row = &xs[hh * LS + w0];
                float4 v = *(const float4*)row;
                float lf = (w0 > 0)      ? row[-1] : 0.f;
                float rt = (w0 + 4 < WW) ? row[4]  : 0.f;
                float k0 = wp[ky * 3 + 0], k1 = wp[ky * 3 + 1], k2 = wp[ky * 3 + 2];
                acc.x = fmaf(k0, lf,  acc.x); acc.y = fmaf(k0, v.x, acc.y);
                acc.z = fmaf(k0, v.y, acc.z); acc.w = fmaf(k0, v.z, acc.w);
                acc.x = fmaf(k1, v.x, acc.x); acc.y = fmaf(k1, v.y, acc.y);
                acc.z = fmaf(k1, v.z, acc.z); acc.w = fmaf(k1, v.w, acc.w);
                acc.x = fmaf(k2, v.y, acc.x); acc.y = fmaf(k2, v.z, acc.y);
                acc.z = fmaf(k2, v.w, acc.z); acc.w = fmaf(k2, rt,  acc.w);
            }
            *(float4*)&x1s[h * LS + w0] = acc;
        }
    }
    __syncthreads();

    const float* kp = kern + (size_t)b * 9 * HW;
    #pragma unroll
    for (int i = 0; i < 4; i++) {
        int h  = r + (i << 4);
        int hw = h * WW + w0;
        float4 acc = make_float4(0.f, 0.f, 0.f, 0.f);
        #pragma unroll
        for (int ky = 0; ky < 3; ky++) {
            int hh = h + ky - 1;
            if (hh < 0 || hh >= HH) continue;
            const float* row = &x1s[hh * LS + w0];
            float4 v = *(const float4*)row;
            float lf = (w0 > 0)      ? row[-1] : 0.f;
            float rt = (w0 + 4 < WW) ? row[4]  : 0.f;
            float4 k0 = *(const float4*)(kp + (ky * 3 + 0) * HW + hw);
            float4 k1 = *(const float4*)(kp + (ky * 3 + 1) * HW + hw);
            float4 k2 = *(const float4*)(kp + (ky * 3 + 2) * HW + hw);
            acc.x = fmaf(k0.x, lf,  acc.x); acc.y = fmaf(k0.y, v.x, acc.y);
            acc.z = fmaf(k0.z, v.y, acc.z); acc.w = fmaf(k0.w, v.z, acc.w);
            acc.x = fmaf(k1.x, v.x, acc.x); acc.y = fmaf(k1.y, v.y, acc.y);
            acc.z = fmaf(k1.z, v.z, acc.z); acc.w = fmaf(k1.w, v.w, acc.w);
            acc.x = fmaf(k2.x, v.y, acc.x); acc.y = fmaf(k2.y, v.z, acc.y);
            acc.z = fmaf(k2.z, v.w, acc.z); acc.w = fmaf(k2.w, rt,  acc.w);
        }
        *(float4*)&xs[h * LS + w0] = acc;       // overwrite x stage (dead)
    }
    __syncthreads();

    const float* wp = w_out + c * 9;             // block-uniform -> s_load
    const float bb = b_out[c];
    float* op = out + ((size_t)(b * CC + c)) * HW;
    #pragma unroll
    for (int i = 0; i < 4; i++) {
        int h = r + (i << 4);
        float4 acc = make_float4(bb, bb, bb, bb);
        #pragma unroll
        for (int ky = 0; ky < 3; ky++) {
            int hh = h + ky - 1;
            if (hh < 0 || hh >= HH) continue;
            const float* row = &xs[hh * LS + w0];
            float4 v = *(const float4*)row;
            float lf = (w0 > 0)      ? row[-1] : 0.f;
            float rt = (w0 + 4 < WW) ? row[4]  : 0.f;
            float k0 = wp[ky * 3 + 0], k1 = wp[ky * 3 + 1], k2 = wp[ky * 3 + 2];
            acc.x = fmaf(k0, lf,  acc.x); acc.y = fmaf(k0, v.x, acc.y);
            acc.z = fmaf(k0, v.y, acc.z); acc.w = fmaf(k0, v.z, acc.w);
            acc.x = fmaf(k1, v.x, acc.x); acc.y = fmaf(k1, v.y, acc.y);
            acc.z = fmaf(k1, v.z, acc.z); acc.w = fmaf(k1, v.w, acc.w);
            acc.x = fmaf(k2, v.y, acc.x); acc.y = fmaf(k2, v.z, acc.y);
            acc.z = fmaf(k2, v.w, acc.z); acc.w = fmaf(k2, rt,  acc.w);
        }
        *(float4*)(op + h * WW + w0) = acc;
    }
}

extern "C" void kernel_launch(void* const* d_in, const int* in_sizes, int n_in,
                              void* d_out, int out_size, void* d_ws, size_t ws_size,
                              hipStream_t stream) {
    const float* x      = (const float*)d_in[0];
    const float* w_in   = (const float*)d_in[1];
    const float* b_in   = (const float*)d_in[2];
    const float* w_red  = (const float*)d_in[3];
    const float* b_red  = (const float*)d_in[4];
    const float* w_span = (const float*)d_in[5];
    const float* b_span = (const float*)d_in[6];
    const float* w_out  = (const float*)d_in[7];
    const float* b_out  = (const float*)d_in[8];
    float* out = (float*)d_out;

    float* kern = (float*)d_ws;                        // 8*9*4096 f
    unsigned short* wtf = (unsigned short*)(kern + (size_t)BB * 9 * HW); // 16384 bf16

    build_wtf<<<64, 256, 0, stream>>>(w_red, wtf);
    dw_kern<<<dim3(HH, BB), 512, 0, stream>>>(x, w_in, b_in, wtf, b_red,
                                              w_span, b_span, kern);
    invol_dw<<<dim3(CC, BB), 256, 0, stream>>>(x, w_in, b_in, kern,
                                               w_out, b_out, out);
}